// Round 10
// baseline (154.453 us; speedup 1.0000x reference)
//
#include <hip/hip_runtime.h>
#include <hip/hip_bf16.h>
#include <math.h>

#define BATCH 16
#define NPTS 1024
#define DIM 64
#define EPSF 0.1f
#define INV_EPS 10.0f
#define MAX_ITER 100
#define THRESHF 0.1f
#define LSTRIDE 72   // shorts; 64+8 pad for b128 LDS reads
#define OSTRIDE 136  // shorts; 128+8 pad

typedef _Float16 h8 __attribute__((ext_vector_type(8)));
typedef short short8v __attribute__((ext_vector_type(8)));
typedef float float4v __attribute__((ext_vector_type(4)));

#define ATOMIC_ST(p, v) \
  __hip_atomic_store((p), (v), __ATOMIC_RELAXED, __HIP_MEMORY_SCOPE_AGENT)
#define ATOMIC_LD(p) \
  __hip_atomic_load((p), __ATOMIC_RELAXED, __HIP_MEMORY_SCOPE_AGENT)

__device__ inline float waveSum(float x) {
#pragma unroll
  for (int off = 32; off; off >>= 1) x += __shfl_xor(x, off, 64);
  return x;
}
__device__ inline float waveMax(float x) {
#pragma unroll
  for (int off = 32; off; off >>= 1) x = fmaxf(x, __shfl_xor(x, off, 64));
  return x;
}

// Single fused cooperative kernel, dual-batch pipelined.
// 256 blocks x 512 threads, 1 block/CU. Block blk serves TWO batches:
// batchA = 2*(blk&7), batchB = batchA+1, slot = blk>>3 (32 blocks/batch,
// 32 K-rows per slab). Per iteration: A(a),flag_a -> A(b),flag_b ->
// stop-check -> poll_a,B(a) -> poll_b,B(b): batch-b compute hides batch-a's
// exchange latency. All protocol state poison-compatible (0xAA): flags
// SIGNED (poison<1), errB "<0" sentinel, colsum zeroed in prologue,
// costPart "+1.0 / <0.5" sentinel. Cross-block data via relaxed agent-scope
// (L3 point) ops; ordering = __syncthreads vmcnt drain + monotonic flags.
__global__ __launch_bounds__(512, 1) void sinkhorn_fused(
    const float* __restrict__ x, const float* __restrict__ y,
    __hip_bfloat16* __restrict__ syh,  // [BATCH*NPTS*DIM] bf16
    float* __restrict__ y2,            // [BATCH*NPTS]
    float* __restrict__ colsum,        // [3][BATCH][NPTS]
    float* __restrict__ deltaPub,      // [2][BATCH][32]
    float* __restrict__ errB,          // [MAX_ITER][BATCH], sentinel <0
    int* __restrict__ flags,           // [BATCH][32], signed, poison<1
    float* __restrict__ costPart,      // [256], sentinel <0.5
    float* __restrict__ out) {
  __shared__ __attribute__((aligned(16))) short xs[64 * LSTRIDE];
  __shared__ __attribute__((aligned(16))) short ysA[128 * LSTRIDE];
  __shared__ __attribute__((aligned(16))) short ysB[128 * LSTRIDE];
  __shared__ __attribute__((aligned(16))) short os[2][32 * OSTRIDE];
  __shared__ __attribute__((aligned(16))) float wV[2][NPTS];
  __shared__ __attribute__((aligned(16))) float vV[2][NPTS];
  __shared__ __attribute__((aligned(16))) float colpart[8][NPTS];
  __shared__ float x2L[64];
  __shared__ float derr[8];
  __shared__ float errbL[BATCH];
  const int t = threadIdx.x;
  const int blk = blockIdx.x;
  const int wave = t >> 6, lane = t & 63;
  const int slot = blk >> 3;           // 0..31
  const int batchA = (blk & 7) * 2;    // batch pair on one XCD-slot
  const int batchB = batchA + 1;
  const float log_mu = logf(1.0f / 1024.0f + 1e-8f);

  // ---- Phase 0: softmax of this block's 32+32 x/y rows ----
#pragma unroll
  for (int rr = 0; rr < 8; rr++) {
    int idx = wave * 8 + rr;  // 0..63: [0,32)=slabA rows, [32,64)=slabB
    int batch = (idx < 32) ? batchA : batchB;
    int gr = batch * NPTS + slot * 32 + (idx & 31);
    // x row -> LDS only
    float xv = x[(size_t)gr * DIM + lane];
    float mx = waveMax(xv);
    float ex = expf(xv - mx);
    float sx = waveSum(ex);
    float px = ex / sx;
    __hip_bfloat16 hbx = (__hip_bfloat16)px;
    xs[idx * LSTRIDE + lane] = *(const short*)&hbx;
    float sqx = waveSum(px * px);
    if (lane == 0) x2L[idx] = sqx;
    // y row -> publish write-through to L3
    float yv = y[(size_t)gr * DIM + lane];
    float my = waveMax(yv);
    float ey = expf(yv - my);
    float sy = waveSum(ey);
    float py = ey / sy;
    __hip_bfloat16 hby = (__hip_bfloat16)py;
    unsigned bits = *(const unsigned short*)&hby;
    unsigned nb = __shfl_down(bits, 1);
    if ((lane & 1) == 0)
      ATOMIC_ST((unsigned*)((unsigned short*)syh + (size_t)gr * DIM + lane),
                bits | (nb << 16));
    float sqy = waveSum(py * py);
    if (lane == 0) ATOMIC_ST(&y2[gr], sqy);
  }
  // zero own colsum slices: 3 buffers x 2 batches x 32 cols
  if (t < 192) {
    int buf = t >> 6, bsel = (t >> 5) & 1, col = slot * 32 + (t & 31);
    int batch = bsel ? batchB : batchA;
    ATOMIC_ST(&colsum[((size_t)buf * BATCH + batch) * NPTS + col], 0.f);
  }
  __syncthreads();  // vmcnt drain: sc1 stores + zeros complete at L3
  if (t == 0) ATOMIC_ST(&flags[batchA * 32 + slot], 1);
  if (t == 1) ATOMIC_ST(&flags[batchB * 32 + slot], 1);
  if (t < 32) {
    while (ATOMIC_LD(&flags[batchA * 32 + t]) < 1) {}
  } else if (t < 64) {
    while (ATOMIC_LD(&flags[batchB * 32 + (t - 32)]) < 1) {}
  }
  __syncthreads();

  // ---- Prologue: build both K slabs (32x1024 fp16 each) into registers ----
  const int m = lane & 15, q = lane >> 4;
  const int g16 = lane >> 4, sub16 = lane & 15;
  const int slabw = wave >> 2;  // slab this wave BUILDS
  const int ws = wave & 3;
  const int rt = ws >> 1, cp = ws & 1;
  short8v a0 = *(const short8v*)&xs[(slabw * 32 + rt * 16 + m) * LSTRIDE + q * 8];
  short8v a1 = *(const short8v*)&xs[(slabw * 32 + rt * 16 + m) * LSTRIDE + 32 + q * 8];
  float xa[4];
#pragma unroll
  for (int reg = 0; reg < 4; reg++)
    xa[reg] = x2L[slabw * 32 + rt * 16 + q * 4 + reg];
  const int batchW = slabw ? batchB : batchA;
  h8 ka[2][4], kb[2][4];  // [slab][row]: rows wave*4+rr, cols 8*lane / 512+8*lane
#pragma unroll
  for (int k = 0; k < 8; k++) {
    // stage 128 y-rows of BOTH batches (cols 128k..128k+128 of K)
    {
      int idx = t;
#pragma unroll
      for (int rep = 0; rep < 4; rep++, idx += 512) {
        int bsel = idx >> 10;
        int r = (idx >> 3) & 127, c = idx & 7;
        int batch = bsel ? batchB : batchA;
        short* dst = (bsel ? ysB : ysA) + r * LSTRIDE + c * 8;
        *(short8v*)dst = *(const short8v*)(
            (const short*)syh + ((size_t)batch * NPTS + 128 * k + r) * DIM + c * 8);
      }
    }
    __syncthreads();
    const short* ys = slabw ? ysB : ysA;
    float4v accv[4];
#pragma unroll
    for (int i = 0; i < 4; i++) {
      int ct = cp * 4 + i;
      short8v b0 = *(const short8v*)&ys[(ct * 16 + m) * LSTRIDE + q * 8];
      short8v b1 = *(const short8v*)&ys[(ct * 16 + m) * LSTRIDE + 32 + q * 8];
      float4v c = {0.f, 0.f, 0.f, 0.f};
      c = __builtin_amdgcn_mfma_f32_16x16x32_bf16(a0, b0, c, 0, 0, 0);
      c = __builtin_amdgcn_mfma_f32_16x16x32_bf16(a1, b1, c, 0, 0, 0);
      accv[i] = c;
    }
#pragma unroll
    for (int i = 0; i < 4; i++) {
      int ct = cp * 4 + i;
      float y2v = y2[(size_t)batchW * NPTS + 128 * k + ct * 16 + m];
#pragma unroll
      for (int reg = 0; reg < 4; reg++) {
        float C = xa[reg] + y2v - 2.0f * accv[i][reg];
        _Float16 kv = (_Float16)expf(-INV_EPS * C);
        os[slabw][(rt * 16 + q * 4 + reg) * OSTRIDE + ct * 16 + m] =
            *(const short*)&kv;
      }
    }
    __syncthreads();
    // consume: chunk k holds cols 128k..+128; thread's ka cols need k==g16,
    // kb cols need k==g16+4; local col = 8*sub16
    if (k < 4) {
      if (g16 == k) {
#pragma unroll
        for (int s = 0; s < 2; s++)
#pragma unroll
          for (int rr = 0; rr < 4; rr++)
            ka[s][rr] = *(const h8*)&os[s][(wave * 4 + rr) * OSTRIDE + sub16 * 8];
      }
    } else {
      if (g16 == k - 4) {
#pragma unroll
        for (int s = 0; s < 2; s++)
#pragma unroll
          for (int rr = 0; rr < 4; rr++)
            kb[s][rr] = *(const h8*)&os[s][(wave * 4 + rr) * OSTRIDE + sub16 * 8];
      }
    }
    __syncthreads();
  }

  for (int j = t; j < NPTS; j += 512) {
    vV[0][j] = 0.f; wV[0][j] = 1.f;
    vV[1][j] = 0.f; wV[1][j] = 1.f;
  }
  __syncthreads();

  float u[2][4], uPrev[2][4];
#pragma unroll
  for (int s = 0; s < 2; s++)
#pragma unroll
    for (int r = 0; r < 4; r++) u[s][r] = 0.f;
  int it = 0;

  while (true) {
#pragma unroll
    for (int s = 0; s < 2; s++)
#pragma unroll
      for (int r = 0; r < 4; r++) uPrev[s][r] = u[s][r];

    // ---- Phase A for both slabs (flag_a lands before A(b) compute) ----
#pragma unroll
    for (int s = 0; s < 2; s++) {
      const int batch = s ? batchB : batchA;
      const float4* w4 = (const float4*)wV[s];
      float wreg[16];
      *(float4*)&wreg[0]  = w4[2 * lane];
      *(float4*)&wreg[4]  = w4[2 * lane + 1];
      *(float4*)&wreg[8]  = w4[128 + 2 * lane];
      *(float4*)&wreg[12] = w4[128 + 2 * lane + 1];
      float colreg[16];
#pragma unroll
      for (int n = 0; n < 16; n++) colreg[n] = 0.f;
      float dl = 0.f;
#pragma unroll
      for (int rr = 0; rr < 4; rr++) {
        float kf[16];
#pragma unroll
        for (int n = 0; n < 8; n++) {
          kf[n] = (float)ka[s][rr][n];
          kf[8 + n] = (float)kb[s][rr][n];
        }
        float dot = 0.f;
#pragma unroll
        for (int n = 0; n < 16; n++) dot = fmaf(kf[n], wreg[n], dot);
        dot = waveSum(dot);
        float uo = u[s][rr];
        float sv = expf(INV_EPS * uo) * dot;
        float un = EPSF * (log_mu - logf(sv + 1e-6f)) + uo;
        dl += fabsf(un - uo);
        u[s][rr] = un;
        float ai = expf(INV_EPS * un);
#pragma unroll
        for (int n = 0; n < 16; n++) colreg[n] = fmaf(kf[n], ai, colreg[n]);
      }
      if (lane == 0) derr[wave] = dl;
      {
        float4* cpv = (float4*)&colpart[wave][0];
        cpv[2 * lane]       = make_float4(colreg[0], colreg[1], colreg[2], colreg[3]);
        cpv[2 * lane + 1]   = make_float4(colreg[4], colreg[5], colreg[6], colreg[7]);
        cpv[128 + 2 * lane] = make_float4(colreg[8], colreg[9], colreg[10], colreg[11]);
        cpv[128 + 2 * lane + 1] = make_float4(colreg[12], colreg[13], colreg[14], colreg[15]);
      }
      __syncthreads();
      float* cs = colsum + ((size_t)(it % 3) * BATCH + batch) * NPTS;
#pragma unroll
      for (int rep = 0; rep < 2; rep++) {
        int j = t + rep * 512;
        float sum = 0.f;
#pragma unroll
        for (int w = 0; w < 8; w++) sum += colpart[w][j];
        unsafeAtomicAdd(&cs[j], sum);
      }
      if (t == 0) {
        float e = 0.f;
#pragma unroll
        for (int w = 0; w < 8; w++) e += derr[w];
        ATOMIC_ST(&deltaPub[((it & 1) * BATCH + batch) * 32 + slot], e);
      }
      __syncthreads();  // colpart reads done + atomics drained at L3
      if (t == 0) ATOMIC_ST(&flags[batch * 32 + slot], it + 2);
    }

    // ---- lag-1 global stop check (ancient errB[it-1], all batches) ----
    if (it >= 1) {
      if (t < BATCH) {
        float v;
        while ((v = ATOMIC_LD(&errB[(it - 1) * BATCH + t])) < 0.f) {}
        errbL[t] = v;
      }
      __syncthreads();
      float errv = 0.f;
#pragma unroll
      for (int k = 0; k < BATCH; k++) errv += errbL[k];
      if (errv * (1.0f / (float)BATCH) < THRESHF) {
        // reference stopped after body it-1: undo this iteration's u update
#pragma unroll
        for (int s = 0; s < 2; s++)
#pragma unroll
          for (int r = 0; r < 4; r++) u[s][r] = uPrev[s][r];
        break;
      }
    }

    // ---- Phase B for both slabs (poll_a hidden behind A(b)+check) ----
#pragma unroll
    for (int s = 0; s < 2; s++) {
      const int batch = s ? batchB : batchA;
      if (t < 32) {
        while (ATOMIC_LD(&flags[batch * 32 + t]) < it + 2) {}
      }
      __syncthreads();
      float* cs = colsum + ((size_t)(it % 3) * BATCH + batch) * NPTS;
      float cs0 = ATOMIC_LD(&cs[t]);
      float cs1 = ATOMIC_LD(&cs[t + 512]);
      // zero buffer for it+2 (peers' it-1 reads done before flagging it+2)
      if (t < 32)
        ATOMIC_ST(&colsum[((size_t)((it + 2) % 3) * BATCH + batch) * NPTS +
                          slot * 32 + t], 0.f);
      if (slot == 0 && t == 0) {
        const float* dp = deltaPub + ((it & 1) * BATCH + batch) * 32;
        float e = 0.f;
#pragma unroll
        for (int k = 0; k < 32; k++) e += ATOMIC_LD((float*)&dp[k]);
        ATOMIC_ST(&errB[it * BATCH + batch], e);
      }
      float vo = vV[s][t];
      float sv = expf(INV_EPS * vo) * cs0;
      float vn = EPSF * (log_mu - logf(sv + 1e-6f)) + vo;
      vV[s][t] = vn;
      wV[s][t] = expf(INV_EPS * vn);
      float vo1 = vV[s][t + 512];
      float sv1 = expf(INV_EPS * vo1) * cs1;
      float vn1 = EPSF * (log_mu - logf(sv1 + 1e-6f)) + vo1;
      vV[s][t + 512] = vn1;
      wV[s][t + 512] = expf(INV_EPS * vn1);
    }
    it++;
    if (it >= MAX_ITER) break;
    __syncthreads();  // w updates visible before next phase A
  }

  // ---- Final cost: pi = a_i*K*w_j, C = -eps*log(K) ----
  {
    __syncthreads();
    float csum = 0.f;
#pragma unroll
    for (int s = 0; s < 2; s++) {
      const float4* w4 = (const float4*)wV[s];
      float wreg[16];
      *(float4*)&wreg[0]  = w4[2 * lane];
      *(float4*)&wreg[4]  = w4[2 * lane + 1];
      *(float4*)&wreg[8]  = w4[128 + 2 * lane];
      *(float4*)&wreg[12] = w4[128 + 2 * lane + 1];
#pragma unroll
      for (int rr = 0; rr < 4; rr++) {
        float kf[16];
#pragma unroll
        for (int n = 0; n < 8; n++) {
          kf[n] = (float)ka[s][rr][n];
          kf[8 + n] = (float)kb[s][rr][n];
        }
        float ai = expf(INV_EPS * u[s][rr]);
#pragma unroll
        for (int n = 0; n < 16; n++) {
          if (kf[n] > 0.f)
            csum += ai * wreg[n] * kf[n] * (-EPSF * logf(kf[n]));
        }
      }
    }
    csum = waveSum(csum);
    if (lane == 0) derr[wave] = csum;
    __syncthreads();
    if (t == 0) {
      float cst = 0.f;
#pragma unroll
      for (int w = 0; w < 8; w++) cst += derr[w];
      ATOMIC_ST(&costPart[blk], cst + 1.0f);  // bias: sentinel-safe vs poison
    }
    if (blk == 0) {
      if (t < 256) {
        float v;
        while ((v = ATOMIC_LD(&costPart[t])) < 0.5f) {}
        colpart[0][t] = v;
      }
      __syncthreads();
      if (wave == 0) {
        float sv = colpart[0][lane] + colpart[0][lane + 64] +
                   colpart[0][lane + 128] + colpart[0][lane + 192];
        sv = waveSum(sv);
        if (lane == 0) out[0] = (sv - 256.0f) * (1.0f / (float)BATCH);
      }
    }
  }
}

extern "C" void kernel_launch(void* const* d_in, const int* in_sizes, int n_in,
                              void* d_out, int out_size, void* d_ws,
                              size_t ws_size, hipStream_t stream) {
  (void)in_sizes; (void)n_in; (void)out_size; (void)ws_size;
  const float* x = (const float*)d_in[0];
  const float* y = (const float*)d_in[1];
  float* out = (float*)d_out;

  char* ws = (char*)d_ws;
  size_t off = 0;
  auto alloc = [&](size_t nbytes) -> void* {
    void* p = (void*)(ws + off);
    off = (off + nbytes + 255) & ~(size_t)255;
    return p;
  };
  __hip_bfloat16* syh = (__hip_bfloat16*)alloc((size_t)BATCH * NPTS * DIM * 2);
  float* y2 = (float*)alloc((size_t)BATCH * NPTS * 4);
  float* colsum = (float*)alloc((size_t)3 * BATCH * NPTS * 4);
  float* deltaPub = (float*)alloc((size_t)2 * BATCH * 32 * 4);
  float* errB = (float*)alloc((size_t)MAX_ITER * BATCH * 4);
  int* flags = (int*)alloc((size_t)BATCH * 32 * 4);
  float* costPart = (float*)alloc(256 * 4);

  void* args[] = {&x, &y, &syh, &y2, &colsum, &deltaPub,
                  &errB, &flags, &costPart, &out};
  hipLaunchCooperativeKernel((void*)sinkhorn_fused, dim3(256), dim3(512), args,
                             0, stream);
}

// Round 11
// 139.397 us; speedup vs baseline: 1.1080x; 1.1080x over previous
//
#include <hip/hip_runtime.h>
#include <hip/hip_bf16.h>
#include <math.h>

#define BATCH 16
#define NPTS 1024
#define DIM 64
#define EPSF 0.1f
#define INV_EPS 10.0f
#define MAX_ITER 100
#define THRESHF 0.1f
#define LSTRIDE 72  // shorts; 64+8 pad keeps b128 LDS reads conflict-cheap

typedef _Float16 h8 __attribute__((ext_vector_type(8)));
typedef _Float16 h2 __attribute__((ext_vector_type(2)));
typedef short short8v __attribute__((ext_vector_type(8)));
typedef float float4v __attribute__((ext_vector_type(4)));

#define ATOMIC_ST(p, v) \
  __hip_atomic_store((p), (v), __ATOMIC_RELAXED, __HIP_MEMORY_SCOPE_AGENT)
#define ATOMIC_LD(p) \
  __hip_atomic_load((p), __ATOMIC_RELAXED, __HIP_MEMORY_SCOPE_AGENT)

__device__ inline float waveSum(float x) {
#pragma unroll
  for (int off = 32; off; off >>= 1) x += __shfl_xor(x, off, 64);
  return x;
}
__device__ inline float waveMax(float x) {
#pragma unroll
  for (int off = 32; off; off >>= 1) x = fmaxf(x, __shfl_xor(x, off, 64));
  return x;
}

__device__ inline float dot2acc(h2 a, h2 b, float c) {
#if __has_builtin(__builtin_amdgcn_fdot2)
  return __builtin_amdgcn_fdot2(a, b, c, false);
#else
  c = fmaf((float)a[0], (float)b[0], c);
  return fmaf((float)a[1], (float)b[1], c);
#endif
}

// Single fused cooperative kernel (R9 protocol: 16 blocks/batch, one flag
// round per iteration, lag-1 stop check). 256 blocks x 512 threads,
// 1 block/CU. Block owns rows [kslot*64,+64) of batch (blk&7)+8*(blk>>7).
// K slab (64x1024 fp16) in registers. w kept packed fp16 in LDS; phase-A
// dot via v_dot2_f32_f16, colreg via mixed-precision fma. flags/errB polls
// run in PARALLEL under one barrier. All protocol state poison-compatible:
// flags SIGNED (poison<1), errB "<0" sentinel, colsum zeroed in prologue,
// costPart "+1.0 / <0.5" sentinel. Cross-block data via relaxed agent-scope
// (L3-point) ops; ordering = __syncthreads vmcnt drain + monotonic flags.
__global__ __launch_bounds__(512, 1) void sinkhorn_fused(
    const float* __restrict__ x, const float* __restrict__ y,
    __hip_bfloat16* __restrict__ syh,  // [BATCH*NPTS*DIM] bf16
    float* __restrict__ y2,            // [BATCH*NPTS]
    float* __restrict__ colsum,        // [3][BATCH][NPTS]
    float* __restrict__ deltaPub,      // [2][BATCH][16]
    float* __restrict__ errB,          // [MAX_ITER][BATCH], sentinel <0
    int* __restrict__ flags,           // [BATCH][16], signed, poison<1
    float* __restrict__ costPart,      // [256], sentinel <0.5
    float* __restrict__ out) {
  __shared__ __attribute__((aligned(16))) short xs[64 * LSTRIDE];
  __shared__ __attribute__((aligned(16))) short ys[2][64 * LSTRIDE];
  __shared__ __attribute__((aligned(16))) short os[2][64 * LSTRIDE];
  __shared__ __attribute__((aligned(16))) _Float16 wH[NPTS];  // packed fp16 w
  __shared__ __attribute__((aligned(16))) float vLDS[NPTS];
  __shared__ __attribute__((aligned(16))) float colpart[8][NPTS];
  __shared__ float x2L[64];
  __shared__ float derr[8];
  __shared__ float errbL[BATCH];
  const int t = threadIdx.x;
  const int blk = blockIdx.x;
  const int wave = t >> 6, lane = t & 63;
  const int batch = (blk & 7) + 8 * (blk >> 7);
  const int kslot = (blk >> 3) & 15;
  const float log_mu = logf(1.0f / 1024.0f + 1e-8f);

  // ---- Phase 0: softmax. x-rows -> LDS only; y-rows -> global via sc1. ----
#pragma unroll
  for (int rr = 0; rr < 8; rr++) {
    int rl = wave * 8 + rr;  // 0..63 local row
    int gr = batch * NPTS + kslot * 64 + rl;
    float xv = x[(size_t)gr * DIM + lane];
    float mx = waveMax(xv);
    float ex = expf(xv - mx);
    float sx = waveSum(ex);
    float px = ex / sx;
    __hip_bfloat16 hbx = (__hip_bfloat16)px;
    xs[rl * LSTRIDE + lane] = *(const short*)&hbx;
    float sqx = waveSum(px * px);
    if (lane == 0) x2L[rl] = sqx;
    float yv = y[(size_t)gr * DIM + lane];
    float my = waveMax(yv);
    float ey = expf(yv - my);
    float sy = waveSum(ey);
    float py = ey / sy;
    __hip_bfloat16 hby = (__hip_bfloat16)py;
    unsigned bits = *(const unsigned short*)&hby;
    unsigned nb = __shfl_down(bits, 1);
    if ((lane & 1) == 0)
      ATOMIC_ST((unsigned*)((unsigned short*)syh + (size_t)gr * DIM + lane),
                bits | (nb << 16));
    float sqy = waveSum(py * py);
    if (lane == 0) ATOMIC_ST(&y2[gr], sqy);
  }
  // zero own colsum slices of all 3 buffers (before any peer can add)
  if (t < 192) {
    int buf = t >> 6, j = kslot * 64 + (t & 63);
    ATOMIC_ST(&colsum[((size_t)buf * BATCH + batch) * NPTS + j], 0.f);
  }
  __syncthreads();  // vmcnt drain: sc1 stores complete at L3
  if (t == 0) ATOMIC_ST(&flags[batch * 16 + kslot], 1);
  if (t < 16) {
    while (ATOMIC_LD(&flags[batch * 16 + t]) < 1) {}
  }
  __syncthreads();

  // ---- Prologue: build K slab (64x1024 fp16) into registers via MFMA ----
  const int m = lane & 15, q = lane >> 4;
  const int g = lane >> 3, sub = lane & 7;
  const int sw = wave & 3, ts = wave >> 2;
  short8v a0 = *(const short8v*)&xs[(sw * 16 + m) * LSTRIDE + q * 8];
  short8v a1 = *(const short8v*)&xs[(sw * 16 + m) * LSTRIDE + 32 + q * 8];
  float xa[4];
#pragma unroll
  for (int reg = 0; reg < 4; reg++) xa[reg] = x2L[sw * 16 + q * 4 + reg];
  h8 ka[8], kb[8];
#pragma unroll
  for (int k = 0; k < 8; k++) {
    {
      int idx = t;
#pragma unroll
      for (int rep = 0; rep < 2; rep++, idx += 512) {
        int r = idx >> 3, c = idx & 7;
        *(short8v*)&ys[r >> 6][(r & 63) * LSTRIDE + c * 8] = *(const short8v*)(
            (const short*)syh + ((size_t)batch * NPTS + 128 * k + r) * DIM + c * 8);
      }
    }
    __syncthreads();
    const int jt = 2 * k + ts;
    float4v accv[4];
#pragma unroll
    for (int tj = 0; tj < 4; tj++) {
      short8v b0 = *(const short8v*)&ys[ts][(tj * 16 + m) * LSTRIDE + q * 8];
      short8v b1 = *(const short8v*)&ys[ts][(tj * 16 + m) * LSTRIDE + 32 + q * 8];
      float4v c = {0.f, 0.f, 0.f, 0.f};
      c = __builtin_amdgcn_mfma_f32_16x16x32_bf16(a0, b0, c, 0, 0, 0);
      c = __builtin_amdgcn_mfma_f32_16x16x32_bf16(a1, b1, c, 0, 0, 0);
      accv[tj] = c;
    }
#pragma unroll
    for (int tj = 0; tj < 4; tj++) {
      float y2v = y2[(size_t)batch * NPTS + jt * 64 + tj * 16 + m];
#pragma unroll
      for (int reg = 0; reg < 4; reg++) {
        float C = xa[reg] + y2v - 2.0f * accv[tj][reg];
        _Float16 kv = (_Float16)expf(-INV_EPS * C);
        os[ts][(sw * 16 + q * 4 + reg) * LSTRIDE + tj * 16 + m] = *(const short*)&kv;
      }
    }
    __syncthreads();
    {
      int e0 = (2 * k) & 7, e1 = (2 * k + 1) & 7;
      if (g == e0 || g == e1) {
        const short* srcp = (g == e0) ? &os[0][0] : &os[1][0];
#pragma unroll
        for (int rr = 0; rr < 8; rr++) {
          h8 v = *(const h8*)&srcp[(wave * 8 + rr) * LSTRIDE + sub * 8];
          if (k < 4) ka[rr] = v; else kb[rr] = v;
        }
      }
    }
    __syncthreads();
  }

  for (int j = t; j < NPTS; j += 512) { vLDS[j] = 0.f; wH[j] = (_Float16)1.0f; }
  __syncthreads();

  float u[8], uPrev[8];
#pragma unroll
  for (int r = 0; r < 8; r++) u[r] = 0.f;
  int it = 0;

  while (true) {
#pragma unroll
    for (int r = 0; r < 8; r++) uPrev[r] = u[r];
    // ---- Phase A: u update + column partials (K in regs, w packed fp16) ----
    const h8* w8 = (const h8*)wH;
    h8 wa = w8[lane];       // cols [8*lane, +8)
    h8 wb = w8[64 + lane];  // cols [512+8*lane, +8)
    float colreg[16];
#pragma unroll
    for (int n = 0; n < 16; n++) colreg[n] = 0.f;
    float delta = 0.f;
#pragma unroll
    for (int rr = 0; rr < 8; rr++) {
      float dot = 0.f;
#pragma unroll
      for (int n = 0; n < 4; n++) {
        dot = dot2acc((h2){ka[rr][2 * n], ka[rr][2 * n + 1]},
                      (h2){wa[2 * n], wa[2 * n + 1]}, dot);
        dot = dot2acc((h2){kb[rr][2 * n], kb[rr][2 * n + 1]},
                      (h2){wb[2 * n], wb[2 * n + 1]}, dot);
      }
      dot = waveSum(dot);
      float uo = u[rr];
      float s = expf(INV_EPS * uo) * dot;
      float un = EPSF * (log_mu - logf(s + 1e-6f)) + uo;
      delta += fabsf(un - uo);
      u[rr] = un;
      float ai = expf(INV_EPS * un);
#pragma unroll
      for (int n = 0; n < 8; n++) {
        colreg[n] = fmaf((float)ka[rr][n], ai, colreg[n]);      // v_fma_mix
        colreg[8 + n] = fmaf((float)kb[rr][n], ai, colreg[8 + n]);
      }
    }
    if (lane == 0) derr[wave] = delta;
    {
      float4* cp = (float4*)&colpart[wave][0];
      cp[2 * lane]       = make_float4(colreg[0], colreg[1], colreg[2], colreg[3]);
      cp[2 * lane + 1]   = make_float4(colreg[4], colreg[5], colreg[6], colreg[7]);
      cp[128 + 2 * lane] = make_float4(colreg[8], colreg[9], colreg[10], colreg[11]);
      cp[128 + 2 * lane + 1] = make_float4(colreg[12], colreg[13], colreg[14], colreg[15]);
    }
    __syncthreads();
    // block partial -> hw f32 atomicAdd into L3-resident colsum (2/thread)
    float* cs = colsum + ((size_t)(it % 3) * BATCH + batch) * NPTS;
#pragma unroll
    for (int rep = 0; rep < 2; rep++) {
      int j = t + rep * 512;
      float s = 0.f;
#pragma unroll
      for (int w = 0; w < 8; w++) s += colpart[w][j];
      unsafeAtomicAdd(&cs[j], s);
    }
    if (t == 0) {
      float e = 0.f;
#pragma unroll
      for (int w = 0; w < 8; w++) e += derr[w];
      ATOMIC_ST(&deltaPub[((it & 1) * BATCH + batch) * 16 + kslot], e);
    }
    __syncthreads();  // vmcnt drain: all waves' adds complete at L3
    if (t == 0) ATOMIC_ST(&flags[batch * 16 + kslot], it + 2);
    // PARALLEL polls: flags (t<16) and lag-1 errB (t in [64,80)) overlap
    if (t < 16) {
      while (ATOMIC_LD(&flags[batch * 16 + t]) < it + 2) {}
    } else if (t >= 64 && t < 64 + BATCH && it >= 1) {
      float v;
      while ((v = ATOMIC_LD(&errB[(it - 1) * BATCH + (t - 64)])) < 0.f) {}
      errbL[t - 64] = v;
    }
    __syncthreads();
    // issue column-sum loads first (critical path; values final per flags)
    float cs0 = ATOMIC_LD(&cs[t]);
    float cs1 = ATOMIC_LD(&cs[t + 512]);
    // zero the buffer for iteration it+2 (race-free per flag chain)
    if (t < 64)
      ATOMIC_ST(&colsum[((size_t)((it + 2) % 3) * BATCH + batch) * NPTS +
                        kslot * 64 + t], 0.f);
    // leader publishes deterministic batch err for iteration it
    if (kslot == 0 && t == 0) {
      const float* dp = deltaPub + ((it & 1) * BATCH + batch) * 16;
      float e = 0.f;
#pragma unroll
      for (int k = 0; k < 16; k++) e += ATOMIC_LD((float*)&dp[k]);
      ATOMIC_ST(&errB[it * BATCH + batch], e);
    }
    // ---- lag-1 global stop decision ----
    if (it >= 1) {
      float errv = 0.f;
#pragma unroll
      for (int k = 0; k < BATCH; k++) errv += errbL[k];
      if (errv * (1.0f / (float)BATCH) < THRESHF) {
        // reference stopped after body it-1: undo this iteration's u update
#pragma unroll
        for (int r = 0; r < 8; r++) u[r] = uPrev[r];
        break;
      }
    }
    // ---- Phase B: v/w update (redundant per block, identical) ----
    {
      float vo = vLDS[t];
      float s = expf(INV_EPS * vo) * cs0;
      float vn = EPSF * (log_mu - logf(s + 1e-6f)) + vo;
      vLDS[t] = vn;
      wH[t] = (_Float16)expf(INV_EPS * vn);
      float vo1 = vLDS[t + 512];
      float s1 = expf(INV_EPS * vo1) * cs1;
      float vn1 = EPSF * (log_mu - logf(s1 + 1e-6f)) + vo1;
      vLDS[t + 512] = vn1;
      wH[t + 512] = (_Float16)expf(INV_EPS * vn1);
    }
    it++;
    if (it >= MAX_ITER) break;
    __syncthreads();  // wH writes visible before next phase A reads
  }

  // ---- Final cost: pi = a_i*K*w_j, C = -eps*log(K) ----
  {
    __syncthreads();
    const h8* w8 = (const h8*)wH;
    h8 wa = w8[lane], wb = w8[64 + lane];
    float csum = 0.f;
#pragma unroll
    for (int rr = 0; rr < 8; rr++) {
      float ai = expf(INV_EPS * u[rr]);
#pragma unroll
      for (int n = 0; n < 8; n++) {
        float kfa = (float)ka[rr][n];
        float kfb = (float)kb[rr][n];
        if (kfa > 0.f)
          csum += ai * (float)wa[n] * kfa * (-EPSF * logf(kfa));
        if (kfb > 0.f)
          csum += ai * (float)wb[n] * kfb * (-EPSF * logf(kfb));
      }
    }
    csum = waveSum(csum);
    if (lane == 0) derr[wave] = csum;
    __syncthreads();
    if (t == 0) {
      float cst = 0.f;
#pragma unroll
      for (int w = 0; w < 8; w++) cst += derr[w];
      ATOMIC_ST(&costPart[blk], cst + 1.0f);  // bias: sentinel-safe vs poison
    }
    // block 0 gathers all 256 partials and writes the scalar output
    if (blk == 0) {
      if (t < 256) {
        float v;
        while ((v = ATOMIC_LD(&costPart[t])) < 0.5f) {}
        colpart[0][t] = v;
      }
      __syncthreads();
      if (wave == 0) {
        float s = colpart[0][lane] + colpart[0][lane + 64] +
                  colpart[0][lane + 128] + colpart[0][lane + 192];
        s = waveSum(s);
        if (lane == 0) out[0] = (s - 256.0f) * (1.0f / (float)BATCH);
      }
    }
  }
}

extern "C" void kernel_launch(void* const* d_in, const int* in_sizes, int n_in,
                              void* d_out, int out_size, void* d_ws,
                              size_t ws_size, hipStream_t stream) {
  (void)in_sizes; (void)n_in; (void)out_size; (void)ws_size;
  const float* x = (const float*)d_in[0];
  const float* y = (const float*)d_in[1];
  float* out = (float*)d_out;

  char* ws = (char*)d_ws;
  size_t off = 0;
  auto alloc = [&](size_t nbytes) -> void* {
    void* p = (void*)(ws + off);
    off = (off + nbytes + 255) & ~(size_t)255;
    return p;
  };
  __hip_bfloat16* syh = (__hip_bfloat16*)alloc((size_t)BATCH * NPTS * DIM * 2);
  float* y2 = (float*)alloc((size_t)BATCH * NPTS * 4);
  float* colsum = (float*)alloc((size_t)3 * BATCH * NPTS * 4);
  float* deltaPub = (float*)alloc((size_t)2 * BATCH * 16 * 4);
  float* errB = (float*)alloc((size_t)MAX_ITER * BATCH * 4);
  int* flags = (int*)alloc((size_t)BATCH * 16 * 4);
  float* costPart = (float*)alloc(256 * 4);

  void* args[] = {&x, &y, &syh, &y2, &colsum, &deltaPub,
                  &errB, &flags, &costPart, &out};
  hipLaunchCooperativeKernel((void*)sinkhorn_fused, dim3(256), dim3(512), args,
                             0, stream);
}